// Round 13
// baseline (466.316 us; speedup 1.0000x reference)
//
#include <hip/hip_runtime.h>

typedef __attribute__((ext_vector_type(8))) short bf16x8;
typedef __attribute__((ext_vector_type(4))) float f32x4;

__device__ __forceinline__ unsigned short f2b(float f) {
    union { float f; unsigned int i; } u; u.f = f;
    return (unsigned short)((u.i + 0x7FFFu + ((u.i >> 16) & 1u)) >> 16);
}
__device__ __forceinline__ unsigned int packbf2(float a, float b) {
    return (unsigned int)f2b(a) | ((unsigned int)f2b(b) << 16);
}

// ---------------------------------------------------------------------------
// SpMM block (device fn): side[r,:] += vals[e] * ego_bf16[cols[e],:]
// (rows sorted). 256 edges per call (4 waves x 64). Metadata via v_readlane;
// row transition = scalar branch; depth-16 register prefetch queue.
// ---------------------------------------------------------------------------
__device__ __forceinline__ void spmm_block(
    const unsigned int* __restrict__ egob, const float* __restrict__ vals,
    const int* __restrict__ rows, const int* __restrict__ cols,
    float* __restrict__ side, int nnz, int blk)
{
    int tid = threadIdx.x;
    int wave = tid >> 6, lane = tid & 63;
    int e0 = blk * 256 + wave * 64;
    if (e0 >= nnz) return;

    int idx = e0 + lane;
    int last = nnz - 1;
    bool ok = idx < nnz;
    int safe = ok ? idx : last;
    int my_row = rows[safe];
    int my_col = cols[safe];
    float my_val = ok ? vals[safe] : 0.f;

    unsigned int pre[16];
    #pragma unroll
    for (int j = 0; j < 16; ++j) {
        unsigned int c = (unsigned int)__builtin_amdgcn_readlane(my_col, j);
        pre[j] = *(egob + ((size_t)c << 6) + lane);
    }

    float ax = 0.f, ay = 0.f;
    int cur = __builtin_amdgcn_readlane(my_row, 0);
    #pragma unroll
    for (int e = 0; e < 64; ++e) {
        int r = __builtin_amdgcn_readlane(my_row, e);
        float vv = __int_as_float(__builtin_amdgcn_readlane(__float_as_int(my_val), e));
        unsigned int u = pre[e & 15];
        if (e < 48) {
            unsigned int c = (unsigned int)__builtin_amdgcn_readlane(my_col, e + 16);
            pre[e & 15] = *(egob + ((size_t)c << 6) + lane);
        }
        if (r != cur) {
            atomicAdd(&side[(size_t)cur * 128 + lane * 2], ax);
            atomicAdd(&side[(size_t)cur * 128 + lane * 2 + 1], ay);
            ax = 0.f; ay = 0.f; cur = r;
        }
        ax = fmaf(vv, __uint_as_float(u << 16), ax);
        ay = fmaf(vv, __uint_as_float(u & 0xFFFF0000u), ay);
    }
    atomicAdd(&side[(size_t)cur * 128 + lane * 2], ax);
    atomicAdd(&side[(size_t)cur * 128 + lane * 2 + 1], ay);
}

#define LDAB 40   // bf16 row stride (gemm2 stage-1 path only)
#define LDBI2 136 // full-K A-tile stride in shorts (128 k + 8 pad; 272B rows
                  // -> 16B-aligned, rows alias banks only 2-way)
#define LDKV 16   // attn K/V LDS stride in words. MUST stay 16 (16B-aligned
                  // float4; R9's 18 caused unaligned ds_read_b128, 4x slower)

// ---------------------------------------------------------------------------
// gemm2 core (LEGACY, stage-1 qkv only -- its transposed weights are being
// produced concurrently in the same stage). f32 W staged via LDS.
// ---------------------------------------------------------------------------
__device__ __forceinline__ void gemm2_core(
    const float* __restrict__ A, const float* __restrict__ W,
    const float* __restrict__ bias, const float* __restrict__ R,
    const float* __restrict__ g, const float* __restrict__ bta,
    float* __restrict__ C, int M, int N, int K, int act,
    int bm, int bn, unsigned short* As, unsigned short* Bs,
    float* redS, float* redSS)
{
    int tid = threadIdx.x, wave = tid >> 6, lane = tid & 63;
    int lm = lane & 15, quad = lane >> 4;
    int wm = wave >> 1, wn = wave & 1;

    f32x4 acc[2][4];
    #pragma unroll
    for (int i = 0; i < 2; ++i)
        #pragma unroll
        for (int j = 0; j < 4; ++j) acc[i][j] = (f32x4)(0.f);

    for (int k0 = 0; k0 < K; k0 += 32) {
        {
            int m = tid >> 2, kc = (tid & 3) * 8;
            const float* p = A + (size_t)(bm + m) * K + k0 + kc;
            float4 a0 = *(const float4*)p, a1 = *(const float4*)(p + 4);
            uint4 pk;
            pk.x = packbf2(a0.x, a0.y); pk.y = packbf2(a0.z, a0.w);
            pk.z = packbf2(a1.x, a1.y); pk.w = packbf2(a1.z, a1.w);
            *(uint4*)&As[m * LDAB + kc] = pk;
        }
        {
            int nn = tid & 127, kh = (tid >> 7) * 16;
            const float* p = W + (size_t)(k0 + kh) * N + bn + nn;
            float w[16];
            #pragma unroll
            for (int j = 0; j < 16; ++j) w[j] = p[(size_t)j * N];
            uint4 pk;
            pk.x = packbf2(w[0], w[1]);  pk.y = packbf2(w[2], w[3]);
            pk.z = packbf2(w[4], w[5]);  pk.w = packbf2(w[6], w[7]);
            *(uint4*)&Bs[nn * LDAB + kh] = pk;
            pk.x = packbf2(w[8], w[9]);  pk.y = packbf2(w[10], w[11]);
            pk.z = packbf2(w[12], w[13]); pk.w = packbf2(w[14], w[15]);
            *(uint4*)&Bs[nn * LDAB + kh + 8] = pk;
        }
        __syncthreads();
        bf16x8 af[2], bfr[4];
        #pragma unroll
        for (int mi = 0; mi < 2; ++mi)
            af[mi] = *(bf16x8*)&As[(wm * 32 + mi * 16 + lm) * LDAB + quad * 8];
        #pragma unroll
        for (int ni = 0; ni < 4; ++ni)
            bfr[ni] = *(bf16x8*)&Bs[(wn * 64 + ni * 16 + lm) * LDAB + quad * 8];
        #pragma unroll
        for (int mi = 0; mi < 2; ++mi)
            #pragma unroll
            for (int ni = 0; ni < 4; ++ni)
                acc[mi][ni] = __builtin_amdgcn_mfma_f32_16x16x32_bf16(
                    af[mi], bfr[ni], acc[mi][ni], 0, 0, 0);
        __syncthreads();
    }

    #pragma unroll
    for (int mi = 0; mi < 2; ++mi)
        #pragma unroll
        for (int r = 0; r < 4; ++r) {
            int row = bm + wm * 32 + mi * 16 + quad * 4 + r;
            #pragma unroll
            for (int ni = 0; ni < 4; ++ni) {
                int col = bn + wn * 64 + ni * 16 + lm;
                float v = acc[mi][ni][r] + bias[col];
                if (R) v += R[(size_t)row * N + col];
                if (act) v = fmaxf(v, 0.f);
                C[(size_t)row * N + col] = v;
            }
        }
    (void)g; (void)bta; (void)redS; (void)redSS;
}

// ---------------------------------------------------------------------------
// gemm3 core: BM=64 x BN=128, 256 threads = 4 waves 2(m)x2(n).
// C = act(A@W + bias [+R]) [+ fused LN], weights PRE-TRANSPOSED bf16 [n][k]
// (B-fragments direct global 16B loads, L2-hot). A staged per 128-k chunk:
// each thread 32 contiguous floats (16 loads in flight), pack, one LDS write,
// ONE barrier, 4 MFMA k-steps. K=128: 2 barriers/tile (was 8); K=512: 8
// (was 32). MFMA order and f2b operands identical to gemm2 -> bit-identical.
// ---------------------------------------------------------------------------
__device__ __forceinline__ void gemm3_core(
    const float* __restrict__ A, const unsigned short* __restrict__ Wt,
    const float* __restrict__ bias, const float* __restrict__ R,
    const float* __restrict__ g, const float* __restrict__ bta,
    float* __restrict__ C, int M, int N, int K, int act,
    int bm, int bn, unsigned short* As, float* redS, float* redSS)
{
    int tid = threadIdx.x, wave = tid >> 6, lane = tid & 63;
    int lm = lane & 15, quad = lane >> 4;
    int wm = wave >> 1, wn = wave & 1;

    f32x4 acc[2][4];
    #pragma unroll
    for (int i = 0; i < 2; ++i)
        #pragma unroll
        for (int j = 0; j < 4; ++j) acc[i][j] = (f32x4)(0.f);

    for (int kch = 0; kch < K; kch += 128) {
        if (kch) __syncthreads();
        {
            int m = tid >> 2, kc = (tid & 3) * 32;
            const float* p = A + (size_t)(bm + m) * K + kch + kc;
            float a[32];
            #pragma unroll
            for (int j = 0; j < 8; ++j) {
                float4 av = *(const float4*)(p + j * 4);
                a[j*4+0] = av.x; a[j*4+1] = av.y; a[j*4+2] = av.z; a[j*4+3] = av.w;
            }
            #pragma unroll
            for (int j = 0; j < 4; ++j) {
                int b0 = j * 8;
                uint4 pk;
                pk.x = packbf2(a[b0+0], a[b0+1]); pk.y = packbf2(a[b0+2], a[b0+3]);
                pk.z = packbf2(a[b0+4], a[b0+5]); pk.w = packbf2(a[b0+6], a[b0+7]);
                *(uint4*)&As[m * LDBI2 + kc + b0] = pk;
            }
        }
        __syncthreads();
        #pragma unroll
        for (int ks = 0; ks < 4; ++ks) {
            bf16x8 af[2], bfr[4];
            #pragma unroll
            for (int mi = 0; mi < 2; ++mi)
                af[mi] = *(bf16x8*)&As[(wm * 32 + mi * 16 + lm) * LDBI2 + ks * 32 + quad * 8];
            #pragma unroll
            for (int ni = 0; ni < 4; ++ni) {
                size_t n = (size_t)(bn + wn * 64 + ni * 16 + lm);
                bfr[ni] = *(const bf16x8*)(Wt + n * K + kch + ks * 32 + quad * 8);
            }
            #pragma unroll
            for (int mi = 0; mi < 2; ++mi)
                #pragma unroll
                for (int ni = 0; ni < 4; ++ni)
                    acc[mi][ni] = __builtin_amdgcn_mfma_f32_16x16x32_bf16(
                        af[mi], bfr[ni], acc[mi][ni], 0, 0, 0);
        }
    }

    #pragma unroll
    for (int mi = 0; mi < 2; ++mi)
        #pragma unroll
        for (int r = 0; r < 4; ++r) {
            int row = bm + wm * 32 + mi * 16 + quad * 4 + r;
            #pragma unroll
            for (int ni = 0; ni < 4; ++ni) {
                int col = bn + wn * 64 + ni * 16 + lm;
                float v = acc[mi][ni][r] + bias[col];
                if (R) v += R[(size_t)row * N + col];
                if (act) v = fmaxf(v, 0.f);
                acc[mi][ni][r] = v;
            }
        }

    if (g) {
        #pragma unroll
        for (int mi = 0; mi < 2; ++mi)
            #pragma unroll
            for (int r = 0; r < 4; ++r) {
                float s = 0.f, ss = 0.f;
                #pragma unroll
                for (int ni = 0; ni < 4; ++ni) {
                    float v = acc[mi][ni][r];
                    s += v; ss = fmaf(v, v, ss);
                }
                #pragma unroll
                for (int off = 1; off < 16; off <<= 1) {
                    s  += __shfl_xor(s, off, 64);
                    ss += __shfl_xor(ss, off, 64);
                }
                if (lm == 0) {
                    int lr = wm * 32 + mi * 16 + quad * 4 + r;
                    redS[wn * 64 + lr] = s;
                    redSS[wn * 64 + lr] = ss;
                }
            }
        __syncthreads();
        #pragma unroll
        for (int mi = 0; mi < 2; ++mi)
            #pragma unroll
            for (int r = 0; r < 4; ++r) {
                int lr = wm * 32 + mi * 16 + quad * 4 + r;
                int row = bm + lr;
                float s = redS[lr] + redS[64 + lr];
                float ss = redSS[lr] + redSS[64 + lr];
                float mean = s * (1.f / 128.f);
                float var = ss * (1.f / 128.f) - mean * mean;
                float rstd = rsqrtf(var + 1e-5f);
                #pragma unroll
                for (int ni = 0; ni < 4; ++ni) {
                    int col = wn * 64 + ni * 16 + lm;
                    float y = (acc[mi][ni][r] - mean) * rstd * g[col] + bta[col];
                    C[(size_t)row * 128 + col] = y;
                }
            }
    } else {
        #pragma unroll
        for (int mi = 0; mi < 2; ++mi)
            #pragma unroll
            for (int r = 0; r < 4; ++r) {
                int row = bm + wm * 32 + mi * 16 + quad * 4 + r;
                #pragma unroll
                for (int ni = 0; ni < 4; ++ni) {
                    int col = bn + wn * 64 + ni * 16 + lm;
                    C[(size_t)row * N + col] = acc[mi][ni][r];
                }
            }
    }
}

// ---------------------------------------------------------------------------
// Bi-interaction core v4 (R11, proven): single-barrier full-K staging +
// pre-transposed bf16 weights.
// ---------------------------------------------------------------------------
__device__ __forceinline__ void bi_core4(
    const float* __restrict__ ego, const float* __restrict__ side,
    const unsigned short* __restrict__ W1t, const unsigned short* __restrict__ W2t,
    const float* __restrict__ b1, const float* __restrict__ b2,
    float* __restrict__ out, int M, int bm,
    unsigned short* Us, unsigned short* Ms)
{
    int tid = threadIdx.x, wave = tid >> 6, lane = tid & 63;
    int lm = lane & 15, quad = lane >> 4;
    int wm = wave >> 1, wn = wave & 1;

    f32x4 acc1[2][4], acc2[2][4];
    #pragma unroll
    for (int i = 0; i < 2; ++i)
        #pragma unroll
        for (int j = 0; j < 4; ++j) { acc1[i][j] = (f32x4)(0.f); acc2[i][j] = (f32x4)(0.f); }

    {
        int m = tid >> 2, kc = (tid & 3) * 32;
        int gm = bm + m;
        float e[32], s[32];
        if (gm < M) {
            const float* pe = ego + (size_t)gm * 128 + kc;
            const float* ps = side + (size_t)gm * 128 + kc;
            #pragma unroll
            for (int j = 0; j < 8; ++j) {
                float4 ev = *(const float4*)(pe + j * 4);
                float4 sv = *(const float4*)(ps + j * 4);
                e[j*4+0] = ev.x; e[j*4+1] = ev.y; e[j*4+2] = ev.z; e[j*4+3] = ev.w;
                s[j*4+0] = sv.x; s[j*4+1] = sv.y; s[j*4+2] = sv.z; s[j*4+3] = sv.w;
            }
        } else {
            #pragma unroll
            for (int j = 0; j < 32; ++j) { e[j] = 0.f; s[j] = 0.f; }
        }
        #pragma unroll
        for (int j = 0; j < 4; ++j) {
            int b0 = j * 8;
            uint4 pu, pv;
            pu.x = packbf2(e[b0+0]+s[b0+0], e[b0+1]+s[b0+1]);
            pu.y = packbf2(e[b0+2]+s[b0+2], e[b0+3]+s[b0+3]);
            pu.z = packbf2(e[b0+4]+s[b0+4], e[b0+5]+s[b0+5]);
            pu.w = packbf2(e[b0+6]+s[b0+6], e[b0+7]+s[b0+7]);
            pv.x = packbf2(e[b0+0]*s[b0+0], e[b0+1]*s[b0+1]);
            pv.y = packbf2(e[b0+2]*s[b0+2], e[b0+3]*s[b0+3]);
            pv.z = packbf2(e[b0+4]*s[b0+4], e[b0+5]*s[b0+5]);
            pv.w = packbf2(e[b0+6]*s[b0+6], e[b0+7]*s[b0+7]);
            *(uint4*)&Us[m * LDBI2 + kc + b0] = pu;
            *(uint4*)&Ms[m * LDBI2 + kc + b0] = pv;
        }
    }
    __syncthreads();

    #pragma unroll
    for (int ks = 0; ks < 4; ++ks) {
        bf16x8 au[2], am[2], bf1[4], bf2[4];
        #pragma unroll
        for (int mi = 0; mi < 2; ++mi) {
            int off = (wm * 32 + mi * 16 + lm) * LDBI2 + ks * 32 + quad * 8;
            au[mi] = *(bf16x8*)&Us[off];
            am[mi] = *(bf16x8*)&Ms[off];
        }
        #pragma unroll
        for (int ni = 0; ni < 4; ++ni) {
            size_t n = (size_t)(wn * 64 + ni * 16 + lm);
            size_t koff = n * 128 + ks * 32 + quad * 8;
            bf1[ni] = *(const bf16x8*)(W1t + koff);
            bf2[ni] = *(const bf16x8*)(W2t + koff);
        }
        #pragma unroll
        for (int mi = 0; mi < 2; ++mi)
            #pragma unroll
            for (int ni = 0; ni < 4; ++ni) {
                acc1[mi][ni] = __builtin_amdgcn_mfma_f32_16x16x32_bf16(
                    au[mi], bf1[ni], acc1[mi][ni], 0, 0, 0);
                acc2[mi][ni] = __builtin_amdgcn_mfma_f32_16x16x32_bf16(
                    am[mi], bf2[ni], acc2[mi][ni], 0, 0, 0);
            }
    }
    #pragma unroll
    for (int mi = 0; mi < 2; ++mi)
        #pragma unroll
        for (int r = 0; r < 4; ++r) {
            int row = bm + wm * 32 + mi * 16 + quad * 4 + r;
            if (row < M) {
                #pragma unroll
                for (int ni = 0; ni < 4; ++ni) {
                    int col = wn * 64 + ni * 16 + lm;
                    float v1 = acc1[mi][ni][r] + b1[col];
                    v1 = v1 > 0.f ? v1 : 0.01f * v1;
                    float v2 = acc2[mi][ni][r] + b2[col];
                    v2 = v2 > 0.f ? v2 : 0.01f * v2;
                    out[(size_t)row * 128 + col] = v1 + v2;
                }
            }
        }
}

// ---------------------------------------------------------------------------
// Attention body: 4x query-parallel (64 queries x 4 key-segments), exact
// flash merge via shfl_xor. LDKV=16 (aligned).
// ---------------------------------------------------------------------------
__device__ __forceinline__ void attn_block(
    const float* __restrict__ q, const float* __restrict__ k,
    const float* __restrict__ v, float* __restrict__ o, int NH,
    int blk, float* Ks, float* Vs)
{
    const int L = 256, DK = 16;
    int bh = blk >> 2, qq = blk & 3;
    int b = bh / NH, h = bh % NH;
    int tid = threadIdx.x;
    int qi = tid >> 2, seg = tid & 3;

    int lq = qq * 64 + qi;
    size_t qbase = ((size_t)(b * L + lq) * NH + h) * DK;
    float qr[16];
    #pragma unroll
    for (int d4 = 0; d4 < 4; ++d4) {
        float4 t = *(const float4*)(q + qbase + d4 * 4);
        qr[d4*4+0] = t.x * 0.25f; qr[d4*4+1] = t.y * 0.25f;
        qr[d4*4+2] = t.z * 0.25f; qr[d4*4+3] = t.w * 0.25f;
    }
    float acc[16];
    #pragma unroll
    for (int d = 0; d < 16; ++d) acc[d] = 0.f;
    float mmax = -1e30f, ssum = 0.f;

    for (int c0 = 0; c0 < L; c0 += 128) {
        __syncthreads();
        for (int i = tid; i < 128 * 4; i += 256) {
            int ll = i >> 2, d4 = (i & 3) * 4;
            size_t gg = ((size_t)(b * L + c0 + ll) * NH + h) * DK + d4;
            *(float4*)&Ks[ll * LDKV + d4] = *(const float4*)(k + gg);
            *(float4*)&Vs[ll * LDKV + d4] = *(const float4*)(v + gg);
        }
        __syncthreads();

        for (int i = 0; i < 32; ++i) {
            int kk = (i << 2) | seg;
            const float* kr = &Ks[kk * LDKV];
            float dot = 0.f;
            #pragma unroll
            for (int d4 = 0; d4 < 4; ++d4) {
                float4 kv = *(const float4*)&kr[d4 * 4];
                dot = fmaf(qr[d4*4+0], kv.x, dot);
                dot = fmaf(qr[d4*4+1], kv.y, dot);
                dot = fmaf(qr[d4*4+2], kv.z, dot);
                dot = fmaf(qr[d4*4+3], kv.w, dot);
            }
            if (dot > mmax) {
                float alpha = __expf(mmax - dot);
                ssum *= alpha;
                #pragma unroll
                for (int d = 0; d < 16; ++d) acc[d] *= alpha;
                mmax = dot;
            }
            float p = __expf(dot - mmax);
            ssum += p;
            const float* vr = &Vs[kk * LDKV];
            #pragma unroll
            for (int d4 = 0; d4 < 4; ++d4) {
                float4 vv = *(const float4*)&vr[d4 * 4];
                acc[d4*4+0] = fmaf(p, vv.x, acc[d4*4+0]);
                acc[d4*4+1] = fmaf(p, vv.y, acc[d4*4+1]);
                acc[d4*4+2] = fmaf(p, vv.z, acc[d4*4+2]);
                acc[d4*4+3] = fmaf(p, vv.w, acc[d4*4+3]);
            }
        }
    }

    float m1 = fmaxf(mmax, __shfl_xor(mmax, 1, 64));
    float m2 = fmaxf(m1, __shfl_xor(m1, 2, 64));
    float f = __expf(mmax - m2);
    float sl = ssum * f;
    sl += __shfl_xor(sl, 1, 64);
    sl += __shfl_xor(sl, 2, 64);
    #pragma unroll
    for (int d = 0; d < 16; ++d) {
        float a = acc[d] * f;
        a += __shfl_xor(a, 1, 64);
        a += __shfl_xor(a, 2, 64);
        acc[d] = a;
    }
    if (seg == 0) {
        float inv = 1.f / sl;
        #pragma unroll
        for (int d4 = 0; d4 < 4; ++d4) {
            float4 t;
            t.x = acc[d4*4+0] * inv; t.y = acc[d4*4+1] * inv;
            t.z = acc[d4*4+2] * inv; t.w = acc[d4*4+3] * inv;
            *(float4*)(o + qbase + d4 * 4) = t;
        }
    }
}

// ---------------------------------------------------------------------------
// Fused kernels. spmm/prologue at HIGH gids (R11: gather-first hurts when
// co-resident); bi tiles at LOW gids (large LDS -> queueing; start first).
// ---------------------------------------------------------------------------

// Stage 1: qkv (legacy gemm2, f32 weights) + prologue roles at high gids:
// zero side, ego->bf16, bi W transpose, encoder weight transposes.
__global__ __launch_bounds__(256) void qkv2_pre(
    const float* __restrict__ A,
    const float* __restrict__ wq, const float* __restrict__ wk, const float* __restrict__ wv,
    const float* __restrict__ bq, const float* __restrict__ bk, const float* __restrict__ bv,
    float* __restrict__ Q, float* __restrict__ Ko, float* __restrict__ V, int M, int encGy,
    float* __restrict__ side, int Nn,
    const float* __restrict__ ego, unsigned int* __restrict__ egob,
    const float* __restrict__ W1, const float* __restrict__ W2,
    unsigned short* __restrict__ W1t, unsigned short* __restrict__ W2t,
    const float* __restrict__ cw1, const float* __restrict__ cw2,
    const float* __restrict__ wo,
    unsigned short* __restrict__ wt, int NL,
    int encN, int ZB, int CB, int WTB, int EWB)
{
    __shared__ unsigned short As[64 * LDAB];
    __shared__ unsigned short Bs[128 * LDAB];
    __shared__ float redS[128], redSS[128];
    int gid = blockIdx.x;
    int tid = threadIdx.x;
    if (gid >= encN) {
        int j = gid - encN;
        if (j < ZB) {
            size_t n4 = (size_t)Nn * 32;
            float4 z = make_float4(0.f, 0.f, 0.f, 0.f);
            for (size_t i = (size_t)j * 256 + tid; i < n4; i += (size_t)ZB * 256)
                ((float4*)side)[i] = z;
        } else if (j < ZB + CB) {
            int c = j - ZB;
            size_t n4 = (size_t)Nn * 32;
            for (size_t i = (size_t)c * 256 + tid; i < n4; i += (size_t)CB * 256) {
                float4 a = *(const float4*)(ego + i * 4);
                uint2 p;
                p.x = packbf2(a.x, a.y);
                p.y = packbf2(a.z, a.w);
                *(uint2*)(egob + i * 2) = p;
            }
        } else if (j < ZB + CB + WTB) {
            // bi weights: W1,W2 (128x128 f32 [k][n]) -> bf16 [n][k]
            int c = j - ZB - CB;
            for (int ch = c * 256 + tid; ch < 4096; ch += WTB * 256) {
                int w = ch >> 11, rem = ch & 2047;
                int n = rem >> 4, k8 = rem & 15;
                const float* src = w ? W2 : W1;
                unsigned short* dst = w ? W2t : W1t;
                float t[8];
                #pragma unroll
                for (int jj = 0; jj < 8; ++jj)
                    t[jj] = src[(size_t)(k8 * 8 + jj) * 128 + n];
                uint4 pk;
                pk.x = packbf2(t[0], t[1]); pk.y = packbf2(t[2], t[3]);
                pk.z = packbf2(t[4], t[5]); pk.w = packbf2(t[6], t[7]);
                *(uint4*)&dst[(size_t)n * 128 + k8 * 8] = pk;
            }
        } else {
            // encoder weights -> bf16 [n][k]. Per layer: wq,wk,wv,wo (128x128),
            // cw1 (128x512), cw2 (512x128). Unit = 8 k-elems for one n.
            int c = j - ZB - CB - WTB;
            int total = NL * 24576;
            for (int u = c * 256 + tid; u < total; u += EWB * 256) {
                int layer = u / 24576, w = u % 24576;
                const float* src; unsigned short* dst; int K, N, n, k8;
                if (w < 8192) {
                    int mi = w >> 11, r = w & 2047;
                    src = (mi == 0 ? wq : mi == 1 ? wk : mi == 2 ? wv : wo)
                          + (size_t)layer * 16384;
                    dst = wt + (size_t)layer * 196608 + mi * 16384;
                    K = 128; N = 128; n = r >> 4; k8 = r & 15;
                } else if (w < 16384) {
                    int r = w - 8192;
                    src = cw1 + (size_t)layer * 65536;
                    dst = wt + (size_t)layer * 196608 + 65536;
                    K = 128; N = 512; n = r >> 4; k8 = r & 15;
                } else {
                    int r = w - 16384;
                    src = cw2 + (size_t)layer * 65536;
                    dst = wt + (size_t)layer * 196608 + 131072;
                    K = 512; N = 128; n = r >> 6; k8 = r & 63;
                }
                float t[8];
                #pragma unroll
                for (int jj = 0; jj < 8; ++jj)
                    t[jj] = src[(size_t)(k8 * 8 + jj) * N + n];
                uint4 pk;
                pk.x = packbf2(t[0], t[1]); pk.y = packbf2(t[2], t[3]);
                pk.z = packbf2(t[4], t[5]); pk.w = packbf2(t[6], t[7]);
                *(uint4*)&dst[(size_t)n * K + k8 * 8] = pk;
            }
        }
        return;
    }
    int sel = gid / encGy, by = gid % encGy;
    const float* W = (sel == 0) ? wq : (sel == 1) ? wk : wv;
    const float* b = (sel == 0) ? bq : (sel == 1) ? bk : bv;
    float* C = (sel == 0) ? Q : (sel == 1) ? Ko : V;
    gemm2_core(A, W, b, nullptr, nullptr, nullptr, C, M, 128, 128, 0,
               by * 64, 0, As, Bs, redS, redSS);
}

// Q/K/V via gemm3 + spmm chunk (spmm at high gids). Wt = layer base; sel
// picks wqT/wkT/wvT at offsets 0/16384/32768.
__global__ __launch_bounds__(256) void qkv3_spmm(
    const float* __restrict__ A, const unsigned short* __restrict__ wtL,
    const float* __restrict__ bq, const float* __restrict__ bk, const float* __restrict__ bv,
    float* __restrict__ Q, float* __restrict__ Ko, float* __restrict__ V, int M, int encGy,
    const unsigned int* __restrict__ egob, const float* __restrict__ vals,
    const int* __restrict__ rows, const int* __restrict__ cols,
    float* __restrict__ side, int nnz, int spmmBase, int encN)
{
    __shared__ unsigned short As[64 * LDBI2];
    __shared__ float redS[128], redSS[128];
    int gid = blockIdx.x;
    if (gid >= encN) {
        spmm_block(egob, vals, rows, cols, side, nnz, spmmBase + gid - encN);
        return;
    }
    int sel = gid / encGy, by = gid % encGy;
    const unsigned short* Wt = wtL + sel * 16384;
    const float* b = (sel == 0) ? bq : (sel == 1) ? bk : bv;
    float* C = (sel == 0) ? Q : (sel == 1) ? Ko : V;
    gemm3_core(A, Wt, b, nullptr, nullptr, nullptr, C, M, 128, 128, 0,
               by * 64, 0, As, redS, redSS);
}

// generic gemm3 (+LN) + spmm chunk (spmm at high gids)
__global__ __launch_bounds__(256) void gemm3_spmm(
    const float* __restrict__ A, const unsigned short* __restrict__ Wt,
    const float* __restrict__ bias, const float* __restrict__ R,
    const float* __restrict__ g, const float* __restrict__ bta,
    float* __restrict__ C, int M, int N, int K, int act, int encGy,
    const unsigned int* __restrict__ egob, const float* __restrict__ vals,
    const int* __restrict__ rows, const int* __restrict__ cols,
    float* __restrict__ side, int nnz, int spmmBase, int encN)
{
    __shared__ unsigned short As[64 * LDBI2];
    __shared__ float redS[128], redSS[128];
    int gid = blockIdx.x;
    if (gid >= encN) {
        spmm_block(egob, vals, rows, cols, side, nnz, spmmBase + gid - encN);
        return;
    }
    int bx = gid / encGy, by = gid % encGy;
    gemm3_core(A, Wt, bias, R, g, bta, C, M, N, K, act,
               by * 64, bx * 128, As, redS, redSS);
}

// generic gemm3 (+LN) + bi tiles (bi at LOW gids, bi_core4)
__global__ __launch_bounds__(256) void gemm3_bi4(
    const float* __restrict__ A, const unsigned short* __restrict__ Wt,
    const float* __restrict__ bias, const float* __restrict__ R,
    const float* __restrict__ g, const float* __restrict__ bta,
    float* __restrict__ C, int M, int N, int K, int act, int encGy,
    const float* __restrict__ ego, const float* __restrict__ side,
    const unsigned short* __restrict__ W1t, const unsigned short* __restrict__ W2t,
    const float* __restrict__ b1, const float* __restrict__ b2,
    float* __restrict__ out, int Mbi, int biBase, int biCnt)
{
    __shared__ uint4 smem4[34816 / 16];   // max(bi4 34816, gemm3 18432)
    char* smem = (char*)smem4;
    int gid = blockIdx.x;
    if (gid < biCnt) {
        int bb = biBase + gid;
        unsigned short* Us = (unsigned short*)smem;
        unsigned short* Ms = (unsigned short*)(smem + 17408);
        bi_core4(ego, side, W1t, W2t, b1, b2, out, Mbi, bb * 64, Us, Ms);
    } else {
        int egid = gid - biCnt;
        unsigned short* As = (unsigned short*)smem;
        float* redS  = (float*)(smem + 17408);
        float* redSS = (float*)(smem + 17408 + 512);
        int bx = egid / encGy, by = egid % encGy;
        gemm3_core(A, Wt, bias, R, g, bta, C, M, N, K, act,
                   by * 64, bx * 128, As, redS, redSS);
    }
}

// Attention + spmm chunk (spmm at high gids)
__global__ __launch_bounds__(256) void attn_spmm(
    const float* __restrict__ q, const float* __restrict__ k,
    const float* __restrict__ v, float* __restrict__ o, int NH,
    const unsigned int* __restrict__ egob, const float* __restrict__ vals,
    const int* __restrict__ rows, const int* __restrict__ cols,
    float* __restrict__ side, int nnz, int spmmBase, int encN)
{
    __shared__ float Ks[128 * LDKV];
    __shared__ float Vs[128 * LDKV];
    int gid = blockIdx.x;
    if (gid >= encN) {
        spmm_block(egob, vals, rows, cols, side, nnz, spmmBase + gid - encN);
        return;
    }
    attn_block(q, k, v, o, NH, gid, Ks, Vs);
}

extern "C" void kernel_launch(void* const* d_in, const int* in_sizes, int n_in,
                              void* d_out, int out_size, void* d_ws, size_t ws_size,
                              hipStream_t stream) {
    const float* ego    = (const float*)d_in[0];
    const float* vals   = (const float*)d_in[1];
    const float* W1     = (const float*)d_in[2];
    const float* b1     = (const float*)d_in[3];
    const float* W2     = (const float*)d_in[4];
    const float* b2     = (const float*)d_in[5];
    const float* enc_in = (const float*)d_in[6];
    const float* wq  = (const float*)d_in[7];
    const float* bq  = (const float*)d_in[8];
    const float* wk  = (const float*)d_in[9];
    const float* bk  = (const float*)d_in[10];
    const float* wv  = (const float*)d_in[11];
    const float* bv  = (const float*)d_in[12];
    const float* wo  = (const float*)d_in[13];
    const float* bo  = (const float*)d_in[14];
    const float* ln1_g = (const float*)d_in[15];
    const float* ln1_b = (const float*)d_in[16];
    const float* cw1 = (const float*)d_in[17];
    const float* cb1 = (const float*)d_in[18];
    const float* cw2 = (const float*)d_in[19];
    const float* cb2 = (const float*)d_in[20];
    const float* ln2_g = (const float*)d_in[21];
    const float* ln2_b = (const float*)d_in[22];
    const int* rows = (const int*)d_in[23];
    const int* cols = (const int*)d_in[24];

    const int D = 128, DI = 512, NH = 8, L = 256;
    const int Nn   = in_sizes[0] / D;        // 100000
    const int nnz  = in_sizes[1];            // 2000000
    const int NL   = in_sizes[7] / (D * D);  // 2
    const int Menc = in_sizes[6] / D;        // 8192 (= B*L)
    const int Bb   = Menc / L;               // 32

    float* ws = (float*)d_ws;
    size_t off = 0;
    float* side = ws + off; off += (size_t)Nn * D;
    float* Qb = ws + off; off += (size_t)Menc * D;
    float* Kb = ws + off; off += (size_t)Menc * D;
    float* Vb = ws + off; off += (size_t)Menc * D;
    float* Ob = ws + off; off += (size_t)Menc * D;
    float* XA = ws + off; off += (size_t)Menc * D;
    float* XB = ws + off; off += (size_t)Menc * D;
    float* Hb = ws + off; off += (size_t)Menc * DI;
    unsigned int* egob = (unsigned int*)(ws + off); off += (size_t)Nn * (D / 2); // bf16 ego
    unsigned short* W1t = (unsigned short*)(ws + off); off += (size_t)D * D / 2; // bf16 W1^T
    unsigned short* W2t = (unsigned short*)(ws + off); off += (size_t)D * D / 2; // bf16 W2^T
    unsigned short* wt  = (unsigned short*)(ws + off); off += (size_t)NL * 196608 / 2; // enc weights bf16 [n][k]

    float* outAgg = (float*)d_out;
    float* outX   = (float*)d_out + (size_t)Nn * D;

    // ---- fused schedule over 5*NL stages:
    //   stage 1:          prologue roles + legacy qkv (gemm2)
    //   stages 2..5NL-2:  spmm chunks (HIGH gids) + gemm3 encoder
    //   last 2 stages:    bi tiles (LOW gids) + gemm3 encoder
    const int spmmBlocks = (nnz + 255) / 256;
    const int nSpmmStages = 5 * NL - 3;
    const int perS = (spmmBlocks + nSpmmStages - 1) / nSpmmStages;
    const int biTiles = (Nn + 63) / 64;
    const int perB = (biTiles + 1) / 2;
    const int biStart = 5 * NL - 1;          // first bi stage index
    const int encGy = Menc / 64;
    const int ZB = 512, CB = 1024, WTB = 16, EWB = 64;
    int sidx = 0, sci = 0, bci = 0;

    const float* x = enc_in;
    for (int i = 0; i < NL; ++i) {
        const size_t wOff = (size_t)i * D * D;
        const unsigned short* wtL = wt + (size_t)i * 196608;
        int base, cnt;
        #define SPMM_CHUNK base = sci * perS; cnt = spmmBlocks - base; \
                           if (cnt < 0) cnt = 0; if (cnt > perS) cnt = perS; sci++
        #define BI_CHUNK   base = bci * perB; cnt = biTiles - base; \
                           if (cnt < 0) cnt = 0; if (cnt > perB) cnt = perB; bci++

        // --- Q/K/V projection ---
        sidx++;
        if (sidx == 1) {
            qkv2_pre<<<3 * encGy + ZB + CB + WTB + EWB, 256, 0, stream>>>(
                x, wq + wOff, wk + wOff, wv + wOff,
                bq + (size_t)i * D, bk + (size_t)i * D, bv + (size_t)i * D,
                Qb, Kb, Vb, Menc, encGy,
                side, Nn, ego, egob, W1, W2, W1t, W2t,
                cw1, cw2, wo, wt, NL, 3 * encGy, ZB, CB, WTB, EWB);
        } else {
            SPMM_CHUNK;
            qkv3_spmm<<<3 * encGy + cnt, 256, 0, stream>>>(
                x, wtL,
                bq + (size_t)i * D, bk + (size_t)i * D, bv + (size_t)i * D,
                Qb, Kb, Vb, Menc, encGy,
                egob, vals, rows, cols, side, nnz, base, 3 * encGy);
        }

        // --- attention (4x query-parallel) --- (always a spmm stage)
        sidx++;
        SPMM_CHUNK;
        attn_spmm<<<Bb * NH * 4 + cnt, 256, 0, stream>>>(
            Qb, Kb, Vb, Ob, NH,
            egob, vals, rows, cols, side, nnz, base, Bb * NH * 4);

        // --- MHA out-proj + residual + LN1 --- (always a spmm stage)
        sidx++;
        SPMM_CHUNK;
        gemm3_spmm<<<encGy + cnt, 256, 0, stream>>>(
            Ob, wtL + 49152, bo + (size_t)i * D, x,
            ln1_g + (size_t)i * D, ln1_b + (size_t)i * D, XA, Menc, D, D, 0, encGy,
            egob, vals, rows, cols, side, nnz, base, encGy);

        // --- FFN up + relu ---
        sidx++;
        if (sidx >= biStart) {
            BI_CHUNK;
            gemm3_bi4<<<4 * encGy + cnt, 256, 0, stream>>>(
                XA, wtL + 65536, cb1 + (size_t)i * DI, nullptr,
                nullptr, nullptr, Hb, Menc, DI, D, 1, encGy,
                ego, side, W1t, W2t, b1, b2, outAgg, Nn, base, cnt);
        } else {
            SPMM_CHUNK;
            gemm3_spmm<<<4 * encGy + cnt, 256, 0, stream>>>(
                XA, wtL + 65536, cb1 + (size_t)i * DI, nullptr,
                nullptr, nullptr, Hb, Menc, DI, D, 1, encGy,
                egob, vals, rows, cols, side, nnz, base, 4 * encGy);
        }

        // --- FFN down + residual + LN2 ---
        sidx++;
        float* dst = (i == NL - 1) ? outX : XB;
        if (sidx >= biStart) {
            BI_CHUNK;
            gemm3_bi4<<<encGy + cnt, 256, 0, stream>>>(
                Hb, wtL + 131072, cb2 + (size_t)i * D, XA,
                ln2_g + (size_t)i * D, ln2_b + (size_t)i * D, dst, Menc, D, DI, 0, encGy,
                ego, side, W1t, W2t, b1, b2, outAgg, Nn, base, cnt);
        } else {
            SPMM_CHUNK;
            gemm3_spmm<<<encGy + cnt, 256, 0, stream>>>(
                Hb, wtL + 131072, cb2 + (size_t)i * D, XA,
                ln2_g + (size_t)i * D, ln2_b + (size_t)i * D, dst, Menc, D, DI, 0, encGy,
                egob, vals, rows, cols, side, nnz, base, encGy);
        }
        #undef SPMM_CHUNK
        #undef BI_CHUNK
        x = XB;
    }
}

// Round 14
// 439.703 us; speedup vs baseline: 1.0605x; 1.0605x over previous
//
#include <hip/hip_runtime.h>

typedef __attribute__((ext_vector_type(8))) short bf16x8;
typedef __attribute__((ext_vector_type(4))) float f32x4;

__device__ __forceinline__ unsigned short f2b(float f) {
    union { float f; unsigned int i; } u; u.f = f;
    return (unsigned short)((u.i + 0x7FFFu + ((u.i >> 16) & 1u)) >> 16);
}
__device__ __forceinline__ unsigned int packbf2(float a, float b) {
    return (unsigned int)f2b(a) | ((unsigned int)f2b(b) << 16);
}

// ---------------------------------------------------------------------------
// SpMM block (device fn): side[r,:] += vals[e] * ego_bf16[cols[e],:]
// (rows sorted). 256 edges per call (4 waves x 64). Metadata via v_readlane;
// row transition = scalar branch; depth-16 register prefetch queue.
// OWNED-ROW STORES: a row entered AND exited within this wave's 64 edges is
// fully owned -> flush with a plain float2 store over the memset zeros
// (no L2 read-modify-write, no serialization). Boundary rows (first row,
// and last row unless rows[e0+64] differs) still use atomicAdd. ~60% of
// flushes convert. owned/cur are wave-uniform -> scalar branch.
// ---------------------------------------------------------------------------
__device__ __forceinline__ void spmm_block(
    const unsigned int* __restrict__ egob, const float* __restrict__ vals,
    const int* __restrict__ rows, const int* __restrict__ cols,
    float* __restrict__ side, int nnz, int blk)
{
    int tid = threadIdx.x;
    int wave = tid >> 6, lane = tid & 63;
    int e0 = blk * 256 + wave * 64;
    if (e0 >= nnz) return;

    int idx = e0 + lane;
    int last = nnz - 1;
    bool ok = idx < nnz;
    int safe = ok ? idx : last;
    int my_row = rows[safe];
    int my_col = cols[safe];
    float my_val = ok ? vals[safe] : 0.f;

    // first row of the NEXT wave (uniform; -1 if this is the last wave)
    int nxt = (e0 + 64 < nnz) ? rows[e0 + 64] : -1;

    unsigned int pre[16];
    #pragma unroll
    for (int j = 0; j < 16; ++j) {
        unsigned int c = (unsigned int)__builtin_amdgcn_readlane(my_col, j);
        pre[j] = *(egob + ((size_t)c << 6) + lane);
    }

    float ax = 0.f, ay = 0.f;
    int cur = __builtin_amdgcn_readlane(my_row, 0);
    bool owned = false;   // true iff cur's first edge lies inside this wave
    #pragma unroll
    for (int e = 0; e < 64; ++e) {
        int r = __builtin_amdgcn_readlane(my_row, e);
        float vv = __int_as_float(__builtin_amdgcn_readlane(__float_as_int(my_val), e));
        unsigned int u = pre[e & 15];
        if (e < 48) {
            unsigned int c = (unsigned int)__builtin_amdgcn_readlane(my_col, e + 16);
            pre[e & 15] = *(egob + ((size_t)c << 6) + lane);
        }
        if (r != cur) {
            if (owned) {
                // row fully contained in this wave: exclusive -> plain store
                *(float2*)&side[(size_t)cur * 128 + lane * 2] = make_float2(ax, ay);
            } else {
                atomicAdd(&side[(size_t)cur * 128 + lane * 2], ax);
                atomicAdd(&side[(size_t)cur * 128 + lane * 2 + 1], ay);
            }
            ax = 0.f; ay = 0.f; cur = r; owned = true;
        }
        ax = fmaf(vv, __uint_as_float(u << 16), ax);
        ay = fmaf(vv, __uint_as_float(u & 0xFFFF0000u), ay);
    }
    if (owned && cur != nxt) {
        *(float2*)&side[(size_t)cur * 128 + lane * 2] = make_float2(ax, ay);
    } else {
        atomicAdd(&side[(size_t)cur * 128 + lane * 2], ax);
        atomicAdd(&side[(size_t)cur * 128 + lane * 2 + 1], ay);
    }
}

#define LDAB 40   // bf16 row stride (gemm2 stage-1 path only)
#define LDBI2 136 // full-K A-tile stride in shorts (128 k + 8 pad; 272B rows
                  // -> 16B-aligned, rows alias banks only 2-way)
#define LDKV 16   // attn K/V LDS stride in words. MUST stay 16 (16B-aligned
                  // float4; R9's 18 caused unaligned ds_read_b128, 4x slower)

// ---------------------------------------------------------------------------
// gemm2 core (LEGACY, stage-1 qkv only -- its transposed weights are being
// produced concurrently in the same stage). f32 W staged via LDS.
// ---------------------------------------------------------------------------
__device__ __forceinline__ void gemm2_core(
    const float* __restrict__ A, const float* __restrict__ W,
    const float* __restrict__ bias, const float* __restrict__ R,
    const float* __restrict__ g, const float* __restrict__ bta,
    float* __restrict__ C, int M, int N, int K, int act,
    int bm, int bn, unsigned short* As, unsigned short* Bs,
    float* redS, float* redSS)
{
    int tid = threadIdx.x, wave = tid >> 6, lane = tid & 63;
    int lm = lane & 15, quad = lane >> 4;
    int wm = wave >> 1, wn = wave & 1;

    f32x4 acc[2][4];
    #pragma unroll
    for (int i = 0; i < 2; ++i)
        #pragma unroll
        for (int j = 0; j < 4; ++j) acc[i][j] = (f32x4)(0.f);

    for (int k0 = 0; k0 < K; k0 += 32) {
        {
            int m = tid >> 2, kc = (tid & 3) * 8;
            const float* p = A + (size_t)(bm + m) * K + k0 + kc;
            float4 a0 = *(const float4*)p, a1 = *(const float4*)(p + 4);
            uint4 pk;
            pk.x = packbf2(a0.x, a0.y); pk.y = packbf2(a0.z, a0.w);
            pk.z = packbf2(a1.x, a1.y); pk.w = packbf2(a1.z, a1.w);
            *(uint4*)&As[m * LDAB + kc] = pk;
        }
        {
            int nn = tid & 127, kh = (tid >> 7) * 16;
            const float* p = W + (size_t)(k0 + kh) * N + bn + nn;
            float w[16];
            #pragma unroll
            for (int j = 0; j < 16; ++j) w[j] = p[(size_t)j * N];
            uint4 pk;
            pk.x = packbf2(w[0], w[1]);  pk.y = packbf2(w[2], w[3]);
            pk.z = packbf2(w[4], w[5]);  pk.w = packbf2(w[6], w[7]);
            *(uint4*)&Bs[nn * LDAB + kh] = pk;
            pk.x = packbf2(w[8], w[9]);  pk.y = packbf2(w[10], w[11]);
            pk.z = packbf2(w[12], w[13]); pk.w = packbf2(w[14], w[15]);
            *(uint4*)&Bs[nn * LDAB + kh + 8] = pk;
        }
        __syncthreads();
        bf16x8 af[2], bfr[4];
        #pragma unroll
        for (int mi = 0; mi < 2; ++mi)
            af[mi] = *(bf16x8*)&As[(wm * 32 + mi * 16 + lm) * LDAB + quad * 8];
        #pragma unroll
        for (int ni = 0; ni < 4; ++ni)
            bfr[ni] = *(bf16x8*)&Bs[(wn * 64 + ni * 16 + lm) * LDAB + quad * 8];
        #pragma unroll
        for (int mi = 0; mi < 2; ++mi)
            #pragma unroll
            for (int ni = 0; ni < 4; ++ni)
                acc[mi][ni] = __builtin_amdgcn_mfma_f32_16x16x32_bf16(
                    af[mi], bfr[ni], acc[mi][ni], 0, 0, 0);
        __syncthreads();
    }

    #pragma unroll
    for (int mi = 0; mi < 2; ++mi)
        #pragma unroll
        for (int r = 0; r < 4; ++r) {
            int row = bm + wm * 32 + mi * 16 + quad * 4 + r;
            #pragma unroll
            for (int ni = 0; ni < 4; ++ni) {
                int col = bn + wn * 64 + ni * 16 + lm;
                float v = acc[mi][ni][r] + bias[col];
                if (R) v += R[(size_t)row * N + col];
                if (act) v = fmaxf(v, 0.f);
                C[(size_t)row * N + col] = v;
            }
        }
    (void)g; (void)bta; (void)redS; (void)redSS;
}

// ---------------------------------------------------------------------------
// gemm3 core: BM=64 x BN=128, weights PRE-TRANSPOSED bf16 [n][k] (direct
// global 16B B-fragment loads, L2-hot). A staged per 128-k chunk, ONE
// barrier per chunk. Bit-identical rounding vs gemm2.
// ---------------------------------------------------------------------------
__device__ __forceinline__ void gemm3_core(
    const float* __restrict__ A, const unsigned short* __restrict__ Wt,
    const float* __restrict__ bias, const float* __restrict__ R,
    const float* __restrict__ g, const float* __restrict__ bta,
    float* __restrict__ C, int M, int N, int K, int act,
    int bm, int bn, unsigned short* As, float* redS, float* redSS)
{
    int tid = threadIdx.x, wave = tid >> 6, lane = tid & 63;
    int lm = lane & 15, quad = lane >> 4;
    int wm = wave >> 1, wn = wave & 1;

    f32x4 acc[2][4];
    #pragma unroll
    for (int i = 0; i < 2; ++i)
        #pragma unroll
        for (int j = 0; j < 4; ++j) acc[i][j] = (f32x4)(0.f);

    for (int kch = 0; kch < K; kch += 128) {
        if (kch) __syncthreads();
        {
            int m = tid >> 2, kc = (tid & 3) * 32;
            const float* p = A + (size_t)(bm + m) * K + kch + kc;
            float a[32];
            #pragma unroll
            for (int j = 0; j < 8; ++j) {
                float4 av = *(const float4*)(p + j * 4);
                a[j*4+0] = av.x; a[j*4+1] = av.y; a[j*4+2] = av.z; a[j*4+3] = av.w;
            }
            #pragma unroll
            for (int j = 0; j < 4; ++j) {
                int b0 = j * 8;
                uint4 pk;
                pk.x = packbf2(a[b0+0], a[b0+1]); pk.y = packbf2(a[b0+2], a[b0+3]);
                pk.z = packbf2(a[b0+4], a[b0+5]); pk.w = packbf2(a[b0+6], a[b0+7]);
                *(uint4*)&As[m * LDBI2 + kc + b0] = pk;
            }
        }
        __syncthreads();
        #pragma unroll
        for (int ks = 0; ks < 4; ++ks) {
            bf16x8 af[2], bfr[4];
            #pragma unroll
            for (int mi = 0; mi < 2; ++mi)
                af[mi] = *(bf16x8*)&As[(wm * 32 + mi * 16 + lm) * LDBI2 + ks * 32 + quad * 8];
            #pragma unroll
            for (int ni = 0; ni < 4; ++ni) {
                size_t n = (size_t)(bn + wn * 64 + ni * 16 + lm);
                bfr[ni] = *(const bf16x8*)(Wt + n * K + kch + ks * 32 + quad * 8);
            }
            #pragma unroll
            for (int mi = 0; mi < 2; ++mi)
                #pragma unroll
                for (int ni = 0; ni < 4; ++ni)
                    acc[mi][ni] = __builtin_amdgcn_mfma_f32_16x16x32_bf16(
                        af[mi], bfr[ni], acc[mi][ni], 0, 0, 0);
        }
    }

    #pragma unroll
    for (int mi = 0; mi < 2; ++mi)
        #pragma unroll
        for (int r = 0; r < 4; ++r) {
            int row = bm + wm * 32 + mi * 16 + quad * 4 + r;
            #pragma unroll
            for (int ni = 0; ni < 4; ++ni) {
                int col = bn + wn * 64 + ni * 16 + lm;
                float v = acc[mi][ni][r] + bias[col];
                if (R) v += R[(size_t)row * N + col];
                if (act) v = fmaxf(v, 0.f);
                acc[mi][ni][r] = v;
            }
        }

    if (g) {
        #pragma unroll
        for (int mi = 0; mi < 2; ++mi)
            #pragma unroll
            for (int r = 0; r < 4; ++r) {
                float s = 0.f, ss = 0.f;
                #pragma unroll
                for (int ni = 0; ni < 4; ++ni) {
                    float v = acc[mi][ni][r];
                    s += v; ss = fmaf(v, v, ss);
                }
                #pragma unroll
                for (int off = 1; off < 16; off <<= 1) {
                    s  += __shfl_xor(s, off, 64);
                    ss += __shfl_xor(ss, off, 64);
                }
                if (lm == 0) {
                    int lr = wm * 32 + mi * 16 + quad * 4 + r;
                    redS[wn * 64 + lr] = s;
                    redSS[wn * 64 + lr] = ss;
                }
            }
        __syncthreads();
        #pragma unroll
        for (int mi = 0; mi < 2; ++mi)
            #pragma unroll
            for (int r = 0; r < 4; ++r) {
                int lr = wm * 32 + mi * 16 + quad * 4 + r;
                int row = bm + lr;
                float s = redS[lr] + redS[64 + lr];
                float ss = redSS[lr] + redSS[64 + lr];
                float mean = s * (1.f / 128.f);
                float var = ss * (1.f / 128.f) - mean * mean;
                float rstd = rsqrtf(var + 1e-5f);
                #pragma unroll
                for (int ni = 0; ni < 4; ++ni) {
                    int col = wn * 64 + ni * 16 + lm;
                    float y = (acc[mi][ni][r] - mean) * rstd * g[col] + bta[col];
                    C[(size_t)row * 128 + col] = y;
                }
            }
    } else {
        #pragma unroll
        for (int mi = 0; mi < 2; ++mi)
            #pragma unroll
            for (int r = 0; r < 4; ++r) {
                int row = bm + wm * 32 + mi * 16 + quad * 4 + r;
                #pragma unroll
                for (int ni = 0; ni < 4; ++ni) {
                    int col = bn + wn * 64 + ni * 16 + lm;
                    C[(size_t)row * N + col] = acc[mi][ni][r];
                }
            }
    }
}

// ---------------------------------------------------------------------------
// Bi-interaction core v4: single-barrier full-K staging + pre-transposed
// bf16 weights.
// ---------------------------------------------------------------------------
__device__ __forceinline__ void bi_core4(
    const float* __restrict__ ego, const float* __restrict__ side,
    const unsigned short* __restrict__ W1t, const unsigned short* __restrict__ W2t,
    const float* __restrict__ b1, const float* __restrict__ b2,
    float* __restrict__ out, int M, int bm,
    unsigned short* Us, unsigned short* Ms)
{
    int tid = threadIdx.x, wave = tid >> 6, lane = tid & 63;
    int lm = lane & 15, quad = lane >> 4;
    int wm = wave >> 1, wn = wave & 1;

    f32x4 acc1[2][4], acc2[2][4];
    #pragma unroll
    for (int i = 0; i < 2; ++i)
        #pragma unroll
        for (int j = 0; j < 4; ++j) { acc1[i][j] = (f32x4)(0.f); acc2[i][j] = (f32x4)(0.f); }

    {
        int m = tid >> 2, kc = (tid & 3) * 32;
        int gm = bm + m;
        float e[32], s[32];
        if (gm < M) {
            const float* pe = ego + (size_t)gm * 128 + kc;
            const float* ps = side + (size_t)gm * 128 + kc;
            #pragma unroll
            for (int j = 0; j < 8; ++j) {
                float4 ev = *(const float4*)(pe + j * 4);
                float4 sv = *(const float4*)(ps + j * 4);
                e[j*4+0] = ev.x; e[j*4+1] = ev.y; e[j*4+2] = ev.z; e[j*4+3] = ev.w;
                s[j*4+0] = sv.x; s[j*4+1] = sv.y; s[j*4+2] = sv.z; s[j*4+3] = sv.w;
            }
        } else {
            #pragma unroll
            for (int j = 0; j < 32; ++j) { e[j] = 0.f; s[j] = 0.f; }
        }
        #pragma unroll
        for (int j = 0; j < 4; ++j) {
            int b0 = j * 8;
            uint4 pu, pv;
            pu.x = packbf2(e[b0+0]+s[b0+0], e[b0+1]+s[b0+1]);
            pu.y = packbf2(e[b0+2]+s[b0+2], e[b0+3]+s[b0+3]);
            pu.z = packbf2(e[b0+4]+s[b0+4], e[b0+5]+s[b0+5]);
            pu.w = packbf2(e[b0+6]+s[b0+6], e[b0+7]+s[b0+7]);
            pv.x = packbf2(e[b0+0]*s[b0+0], e[b0+1]*s[b0+1]);
            pv.y = packbf2(e[b0+2]*s[b0+2], e[b0+3]*s[b0+3]);
            pv.z = packbf2(e[b0+4]*s[b0+4], e[b0+5]*s[b0+5]);
            pv.w = packbf2(e[b0+6]*s[b0+6], e[b0+7]*s[b0+7]);
            *(uint4*)&Us[m * LDBI2 + kc + b0] = pu;
            *(uint4*)&Ms[m * LDBI2 + kc + b0] = pv;
        }
    }
    __syncthreads();

    #pragma unroll
    for (int ks = 0; ks < 4; ++ks) {
        bf16x8 au[2], am[2], bf1[4], bf2[4];
        #pragma unroll
        for (int mi = 0; mi < 2; ++mi) {
            int off = (wm * 32 + mi * 16 + lm) * LDBI2 + ks * 32 + quad * 8;
            au[mi] = *(bf16x8*)&Us[off];
            am[mi] = *(bf16x8*)&Ms[off];
        }
        #pragma unroll
        for (int ni = 0; ni < 4; ++ni) {
            size_t n = (size_t)(wn * 64 + ni * 16 + lm);
            size_t koff = n * 128 + ks * 32 + quad * 8;
            bf1[ni] = *(const bf16x8*)(W1t + koff);
            bf2[ni] = *(const bf16x8*)(W2t + koff);
        }
        #pragma unroll
        for (int mi = 0; mi < 2; ++mi)
            #pragma unroll
            for (int ni = 0; ni < 4; ++ni) {
                acc1[mi][ni] = __builtin_amdgcn_mfma_f32_16x16x32_bf16(
                    au[mi], bf1[ni], acc1[mi][ni], 0, 0, 0);
                acc2[mi][ni] = __builtin_amdgcn_mfma_f32_16x16x32_bf16(
                    am[mi], bf2[ni], acc2[mi][ni], 0, 0, 0);
            }
    }
    #pragma unroll
    for (int mi = 0; mi < 2; ++mi)
        #pragma unroll
        for (int r = 0; r < 4; ++r) {
            int row = bm + wm * 32 + mi * 16 + quad * 4 + r;
            if (row < M) {
                #pragma unroll
                for (int ni = 0; ni < 4; ++ni) {
                    int col = wn * 64 + ni * 16 + lm;
                    float v1 = acc1[mi][ni][r] + b1[col];
                    v1 = v1 > 0.f ? v1 : 0.01f * v1;
                    float v2 = acc2[mi][ni][r] + b2[col];
                    v2 = v2 > 0.f ? v2 : 0.01f * v2;
                    out[(size_t)row * 128 + col] = v1 + v2;
                }
            }
        }
}

// ---------------------------------------------------------------------------
// Attention body: 4x query-parallel (64 queries x 4 key-segments), exact
// flash merge via shfl_xor. LDKV=16 (aligned).
// ---------------------------------------------------------------------------
__device__ __forceinline__ void attn_block(
    const float* __restrict__ q, const float* __restrict__ k,
    const float* __restrict__ v, float* __restrict__ o, int NH,
    int blk, float* Ks, float* Vs)
{
    const int L = 256, DK = 16;
    int bh = blk >> 2, qq = blk & 3;
    int b = bh / NH, h = bh % NH;
    int tid = threadIdx.x;
    int qi = tid >> 2, seg = tid & 3;

    int lq = qq * 64 + qi;
    size_t qbase = ((size_t)(b * L + lq) * NH + h) * DK;
    float qr[16];
    #pragma unroll
    for (int d4 = 0; d4 < 4; ++d4) {
        float4 t = *(const float4*)(q + qbase + d4 * 4);
        qr[d4*4+0] = t.x * 0.25f; qr[d4*4+1] = t.y * 0.25f;
        qr[d4*4+2] = t.z * 0.25f; qr[d4*4+3] = t.w * 0.25f;
    }
    float acc[16];
    #pragma unroll
    for (int d = 0; d < 16; ++d) acc[d] = 0.f;
    float mmax = -1e30f, ssum = 0.f;

    for (int c0 = 0; c0 < L; c0 += 128) {
        __syncthreads();
        for (int i = tid; i < 128 * 4; i += 256) {
            int ll = i >> 2, d4 = (i & 3) * 4;
            size_t gg = ((size_t)(b * L + c0 + ll) * NH + h) * DK + d4;
            *(float4*)&Ks[ll * LDKV + d4] = *(const float4*)(k + gg);
            *(float4*)&Vs[ll * LDKV + d4] = *(const float4*)(v + gg);
        }
        __syncthreads();

        for (int i = 0; i < 32; ++i) {
            int kk = (i << 2) | seg;
            const float* kr = &Ks[kk * LDKV];
            float dot = 0.f;
            #pragma unroll
            for (int d4 = 0; d4 < 4; ++d4) {
                float4 kv = *(const float4*)&kr[d4 * 4];
                dot = fmaf(qr[d4*4+0], kv.x, dot);
                dot = fmaf(qr[d4*4+1], kv.y, dot);
                dot = fmaf(qr[d4*4+2], kv.z, dot);
                dot = fmaf(qr[d4*4+3], kv.w, dot);
            }
            if (dot > mmax) {
                float alpha = __expf(mmax - dot);
                ssum *= alpha;
                #pragma unroll
                for (int d = 0; d < 16; ++d) acc[d] *= alpha;
                mmax = dot;
            }
            float p = __expf(dot - mmax);
            ssum += p;
            const float* vr = &Vs[kk * LDKV];
            #pragma unroll
            for (int d4 = 0; d4 < 4; ++d4) {
                float4 vv = *(const float4*)&vr[d4 * 4];
                acc[d4*4+0] = fmaf(p, vv.x, acc[d4*4+0]);
                acc[d4*4+1] = fmaf(p, vv.y, acc[d4*4+1]);
                acc[d4*4+2] = fmaf(p, vv.z, acc[d4*4+2]);
                acc[d4*4+3] = fmaf(p, vv.w, acc[d4*4+3]);
            }
        }
    }

    float m1 = fmaxf(mmax, __shfl_xor(mmax, 1, 64));
    float m2 = fmaxf(m1, __shfl_xor(m1, 2, 64));
    float f = __expf(mmax - m2);
    float sl = ssum * f;
    sl += __shfl_xor(sl, 1, 64);
    sl += __shfl_xor(sl, 2, 64);
    #pragma unroll
    for (int d = 0; d < 16; ++d) {
        float a = acc[d] * f;
        a += __shfl_xor(a, 1, 64);
        a += __shfl_xor(a, 2, 64);
        acc[d] = a;
    }
    if (seg == 0) {
        float inv = 1.f / sl;
        #pragma unroll
        for (int d4 = 0; d4 < 4; ++d4) {
            float4 t;
            t.x = acc[d4*4+0] * inv; t.y = acc[d4*4+1] * inv;
            t.z = acc[d4*4+2] * inv; t.w = acc[d4*4+3] * inv;
            *(float4*)(o + qbase + d4 * 4) = t;
        }
    }
}

// ---------------------------------------------------------------------------
// Fused kernels. spmm/prologue at HIGH gids; bi tiles at LOW gids.
// ---------------------------------------------------------------------------

// Stage 1: qkv (legacy gemm2) + prologue roles at high gids.
__global__ __launch_bounds__(256) void qkv2_pre(
    const float* __restrict__ A,
    const float* __restrict__ wq, const float* __restrict__ wk, const float* __restrict__ wv,
    const float* __restrict__ bq, const float* __restrict__ bk, const float* __restrict__ bv,
    float* __restrict__ Q, float* __restrict__ Ko, float* __restrict__ V, int M, int encGy,
    float* __restrict__ side, int Nn,
    const float* __restrict__ ego, unsigned int* __restrict__ egob,
    const float* __restrict__ W1, const float* __restrict__ W2,
    unsigned short* __restrict__ W1t, unsigned short* __restrict__ W2t,
    const float* __restrict__ cw1, const float* __restrict__ cw2,
    const float* __restrict__ wo,
    unsigned short* __restrict__ wt, int NL,
    int encN, int ZB, int CB, int WTB, int EWB)
{
    __shared__ unsigned short As[64 * LDAB];
    __shared__ unsigned short Bs[128 * LDAB];
    __shared__ float redS[128], redSS[128];
    int gid = blockIdx.x;
    int tid = threadIdx.x;
    if (gid >= encN) {
        int j = gid - encN;
        if (j < ZB) {
            size_t n4 = (size_t)Nn * 32;
            float4 z = make_float4(0.f, 0.f, 0.f, 0.f);
            for (size_t i = (size_t)j * 256 + tid; i < n4; i += (size_t)ZB * 256)
                ((float4*)side)[i] = z;
        } else if (j < ZB + CB) {
            int c = j - ZB;
            size_t n4 = (size_t)Nn * 32;
            for (size_t i = (size_t)c * 256 + tid; i < n4; i += (size_t)CB * 256) {
                float4 a = *(const float4*)(ego + i * 4);
                uint2 p;
                p.x = packbf2(a.x, a.y);
                p.y = packbf2(a.z, a.w);
                *(uint2*)(egob + i * 2) = p;
            }
        } else if (j < ZB + CB + WTB) {
            int c = j - ZB - CB;
            for (int ch = c * 256 + tid; ch < 4096; ch += WTB * 256) {
                int w = ch >> 11, rem = ch & 2047;
                int n = rem >> 4, k8 = rem & 15;
                const float* src = w ? W2 : W1;
                unsigned short* dst = w ? W2t : W1t;
                float t[8];
                #pragma unroll
                for (int jj = 0; jj < 8; ++jj)
                    t[jj] = src[(size_t)(k8 * 8 + jj) * 128 + n];
                uint4 pk;
                pk.x = packbf2(t[0], t[1]); pk.y = packbf2(t[2], t[3]);
                pk.z = packbf2(t[4], t[5]); pk.w = packbf2(t[6], t[7]);
                *(uint4*)&dst[(size_t)n * 128 + k8 * 8] = pk;
            }
        } else {
            int c = j - ZB - CB - WTB;
            int total = NL * 24576;
            for (int u = c * 256 + tid; u < total; u += EWB * 256) {
                int layer = u / 24576, w = u % 24576;
                const float* src; unsigned short* dst; int K, N, n, k8;
                if (w < 8192) {
                    int mi = w >> 11, r = w & 2047;
                    src = (mi == 0 ? wq : mi == 1 ? wk : mi == 2 ? wv : wo)
                          + (size_t)layer * 16384;
                    dst = wt + (size_t)layer * 196608 + mi * 16384;
                    K = 128; N = 128; n = r >> 4; k8 = r & 15;
                } else if (w < 16384) {
                    int r = w - 8192;
                    src = cw1 + (size_t)layer * 65536;
                    dst = wt + (size_t)layer * 196608 + 65536;
                    K = 128; N = 512; n = r >> 4; k8 = r & 15;
                } else {
                    int r = w - 16384;
                    src = cw2 + (size_t)layer * 65536;
                    dst = wt + (size_t)layer * 196608 + 131072;
                    K = 512; N = 128; n = r >> 6; k8 = r & 63;
                }
                float t[8];
                #pragma unroll
                for (int jj = 0; jj < 8; ++jj)
                    t[jj] = src[(size_t)(k8 * 8 + jj) * N + n];
                uint4 pk;
                pk.x = packbf2(t[0], t[1]); pk.y = packbf2(t[2], t[3]);
                pk.z = packbf2(t[4], t[5]); pk.w = packbf2(t[6], t[7]);
                *(uint4*)&dst[(size_t)n * K + k8 * 8] = pk;
            }
        }
        return;
    }
    int sel = gid / encGy, by = gid % encGy;
    const float* W = (sel == 0) ? wq : (sel == 1) ? wk : wv;
    const float* b = (sel == 0) ? bq : (sel == 1) ? bk : bv;
    float* C = (sel == 0) ? Q : (sel == 1) ? Ko : V;
    gemm2_core(A, W, b, nullptr, nullptr, nullptr, C, M, 128, 128, 0,
               by * 64, 0, As, Bs, redS, redSS);
}

// Q/K/V via gemm3 + spmm chunk (spmm at high gids).
__global__ __launch_bounds__(256) void qkv3_spmm(
    const float* __restrict__ A, const unsigned short* __restrict__ wtL,
    const float* __restrict__ bq, const float* __restrict__ bk, const float* __restrict__ bv,
    float* __restrict__ Q, float* __restrict__ Ko, float* __restrict__ V, int M, int encGy,
    const unsigned int* __restrict__ egob, const float* __restrict__ vals,
    const int* __restrict__ rows, const int* __restrict__ cols,
    float* __restrict__ side, int nnz, int spmmBase, int encN)
{
    __shared__ unsigned short As[64 * LDBI2];
    __shared__ float redS[128], redSS[128];
    int gid = blockIdx.x;
    if (gid >= encN) {
        spmm_block(egob, vals, rows, cols, side, nnz, spmmBase + gid - encN);
        return;
    }
    int sel = gid / encGy, by = gid % encGy;
    const unsigned short* Wt = wtL + sel * 16384;
    const float* b = (sel == 0) ? bq : (sel == 1) ? bk : bv;
    float* C = (sel == 0) ? Q : (sel == 1) ? Ko : V;
    gemm3_core(A, Wt, b, nullptr, nullptr, nullptr, C, M, 128, 128, 0,
               by * 64, 0, As, redS, redSS);
}

// generic gemm3 (+LN) + spmm chunk (spmm at high gids)
__global__ __launch_bounds__(256) void gemm3_spmm(
    const float* __restrict__ A, const unsigned short* __restrict__ Wt,
    const float* __restrict__ bias, const float* __restrict__ R,
    const float* __restrict__ g, const float* __restrict__ bta,
    float* __restrict__ C, int M, int N, int K, int act, int encGy,
    const unsigned int* __restrict__ egob, const float* __restrict__ vals,
    const int* __restrict__ rows, const int* __restrict__ cols,
    float* __restrict__ side, int nnz, int spmmBase, int encN)
{
    __shared__ unsigned short As[64 * LDBI2];
    __shared__ float redS[128], redSS[128];
    int gid = blockIdx.x;
    if (gid >= encN) {
        spmm_block(egob, vals, rows, cols, side, nnz, spmmBase + gid - encN);
        return;
    }
    int bx = gid / encGy, by = gid % encGy;
    gemm3_core(A, Wt, bias, R, g, bta, C, M, N, K, act,
               by * 64, bx * 128, As, redS, redSS);
}

// generic gemm3 (+LN) + bi tiles (bi at LOW gids, bi_core4)
__global__ __launch_bounds__(256) void gemm3_bi4(
    const float* __restrict__ A, const unsigned short* __restrict__ Wt,
    const float* __restrict__ bias, const float* __restrict__ R,
    const float* __restrict__ g, const float* __restrict__ bta,
    float* __restrict__ C, int M, int N, int K, int act, int encGy,
    const float* __restrict__ ego, const float* __restrict__ side,
    const unsigned short* __restrict__ W1t, const unsigned short* __restrict__ W2t,
    const float* __restrict__ b1, const float* __restrict__ b2,
    float* __restrict__ out, int Mbi, int biBase, int biCnt)
{
    __shared__ uint4 smem4[34816 / 16];   // max(bi4 34816, gemm3 18432)
    char* smem = (char*)smem4;
    int gid = blockIdx.x;
    if (gid < biCnt) {
        int bb = biBase + gid;
        unsigned short* Us = (unsigned short*)smem;
        unsigned short* Ms = (unsigned short*)(smem + 17408);
        bi_core4(ego, side, W1t, W2t, b1, b2, out, Mbi, bb * 64, Us, Ms);
    } else {
        int egid = gid - biCnt;
        unsigned short* As = (unsigned short*)smem;
        float* redS  = (float*)(smem + 17408);
        float* redSS = (float*)(smem + 17408 + 512);
        int bx = egid / encGy, by = egid % encGy;
        gemm3_core(A, Wt, bias, R, g, bta, C, M, N, K, act,
                   by * 64, bx * 128, As, redS, redSS);
    }
}

// Attention + spmm chunk (spmm at high gids)
__global__ __launch_bounds__(256) void attn_spmm(
    const float* __restrict__ q, const float* __restrict__ k,
    const float* __restrict__ v, float* __restrict__ o, int NH,
    const unsigned int* __restrict__ egob, const float* __restrict__ vals,
    const int* __restrict__ rows, const int* __restrict__ cols,
    float* __restrict__ side, int nnz, int spmmBase, int encN)
{
    __shared__ float Ks[128 * LDKV];
    __shared__ float Vs[128 * LDKV];
    int gid = blockIdx.x;
    if (gid >= encN) {
        spmm_block(egob, vals, rows, cols, side, nnz, spmmBase + gid - encN);
        return;
    }
    attn_block(q, k, v, o, NH, gid, Ks, Vs);
}

extern "C" void kernel_launch(void* const* d_in, const int* in_sizes, int n_in,
                              void* d_out, int out_size, void* d_ws, size_t ws_size,
                              hipStream_t stream) {
    const float* ego    = (const float*)d_in[0];
    const float* vals   = (const float*)d_in[1];
    const float* W1     = (const float*)d_in[2];
    const float* b1     = (const float*)d_in[3];
    const float* W2     = (const float*)d_in[4];
    const float* b2     = (const float*)d_in[5];
    const float* enc_in = (const float*)d_in[6];
    const float* wq  = (const float*)d_in[7];
    const float* bq  = (const float*)d_in[8];
    const float* wk  = (const float*)d_in[9];
    const float* bk  = (const float*)d_in[10];
    const float* wv  = (const float*)d_in[11];
    const float* bv  = (const float*)d_in[12];
    const float* wo  = (const float*)d_in[13];
    const float* bo  = (const float*)d_in[14];
    const float* ln1_g = (const float*)d_in[15];
    const float* ln1_b = (const float*)d_in[16];
    const float* cw1 = (const float*)d_in[17];
    const float* cb1 = (const float*)d_in[18];
    const float* cw2 = (const float*)d_in[19];
    const float* cb2 = (const float*)d_in[20];
    const float* ln2_g = (const float*)d_in[21];
    const float* ln2_b = (const float*)d_in[22];
    const int* rows = (const int*)d_in[23];
    const int* cols = (const int*)d_in[24];

    const int D = 128, DI = 512, NH = 8, L = 256;
    const int Nn   = in_sizes[0] / D;        // 100000
    const int nnz  = in_sizes[1];            // 2000000
    const int NL   = in_sizes[7] / (D * D);  // 2
    const int Menc = in_sizes[6] / D;        // 8192 (= B*L)
    const int Bb   = Menc / L;               // 32

    float* ws = (float*)d_ws;
    size_t off = 0;
    float* side = ws + off; off += (size_t)Nn * D;
    float* Qb = ws + off; off += (size_t)Menc * D;
    float* Kb = ws + off; off += (size_t)Menc * D;
    float* Vb = ws + off; off += (size_t)Menc * D;
    float* Ob = ws + off; off += (size_t)Menc * D;
    float* XA = ws + off; off += (size_t)Menc * D;
    float* XB = ws + off; off += (size_t)Menc * D;
    float* Hb = ws + off; off += (size_t)Menc * DI;
    unsigned int* egob = (unsigned int*)(ws + off); off += (size_t)Nn * (D / 2); // bf16 ego
    unsigned short* W1t = (unsigned short*)(ws + off); off += (size_t)D * D / 2; // bf16 W1^T
    unsigned short* W2t = (unsigned short*)(ws + off); off += (size_t)D * D / 2; // bf16 W2^T
    unsigned short* wt  = (unsigned short*)(ws + off); off += (size_t)NL * 196608 / 2; // enc weights bf16 [n][k]

    float* outAgg = (float*)d_out;
    float* outX   = (float*)d_out + (size_t)Nn * D;

    // ---- fused schedule over 5*NL stages:
    //   stage 1:          prologue roles + legacy qkv (gemm2)
    //   stages 2..5NL-2:  spmm chunks (HIGH gids) + gemm3 encoder
    //   last 2 stages:    bi tiles (LOW gids) + gemm3 encoder
    const int spmmBlocks = (nnz + 255) / 256;
    const int nSpmmStages = 5 * NL - 3;
    const int perS = (spmmBlocks + nSpmmStages - 1) / nSpmmStages;
    const int biTiles = (Nn + 63) / 64;
    const int perB = (biTiles + 1) / 2;
    const int biStart = 5 * NL - 1;          // first bi stage index
    const int encGy = Menc / 64;
    const int ZB = 512, CB = 1024, WTB = 16, EWB = 64;
    int sidx = 0, sci = 0, bci = 0;

    const float* x = enc_in;
    for (int i = 0; i < NL; ++i) {
        const size_t wOff = (size_t)i * D * D;
        const unsigned short* wtL = wt + (size_t)i * 196608;
        int base, cnt;
        #define SPMM_CHUNK base = sci * perS; cnt = spmmBlocks - base; \
                           if (cnt < 0) cnt = 0; if (cnt > perS) cnt = perS; sci++
        #define BI_CHUNK   base = bci * perB; cnt = biTiles - base; \
                           if (cnt < 0) cnt = 0; if (cnt > perB) cnt = perB; bci++

        // --- Q/K/V projection ---
        sidx++;
        if (sidx == 1) {
            qkv2_pre<<<3 * encGy + ZB + CB + WTB + EWB, 256, 0, stream>>>(
                x, wq + wOff, wk + wOff, wv + wOff,
                bq + (size_t)i * D, bk + (size_t)i * D, bv + (size_t)i * D,
                Qb, Kb, Vb, Menc, encGy,
                side, Nn, ego, egob, W1, W2, W1t, W2t,
                cw1, cw2, wo, wt, NL, 3 * encGy, ZB, CB, WTB, EWB);
        } else {
            SPMM_CHUNK;
            qkv3_spmm<<<3 * encGy + cnt, 256, 0, stream>>>(
                x, wtL,
                bq + (size_t)i * D, bk + (size_t)i * D, bv + (size_t)i * D,
                Qb, Kb, Vb, Menc, encGy,
                egob, vals, rows, cols, side, nnz, base, 3 * encGy);
        }

        // --- attention (4x query-parallel) --- (always a spmm stage)
        sidx++;
        SPMM_CHUNK;
        attn_spmm<<<Bb * NH * 4 + cnt, 256, 0, stream>>>(
            Qb, Kb, Vb, Ob, NH,
            egob, vals, rows, cols, side, nnz, base, Bb * NH * 4);

        // --- MHA out-proj + residual + LN1 --- (always a spmm stage)
        sidx++;
        SPMM_CHUNK;
        gemm3_spmm<<<encGy + cnt, 256, 0, stream>>>(
            Ob, wtL + 49152, bo + (size_t)i * D, x,
            ln1_g + (size_t)i * D, ln1_b + (size_t)i * D, XA, Menc, D, D, 0, encGy,
            egob, vals, rows, cols, side, nnz, base, encGy);

        // --- FFN up + relu ---
        sidx++;
        if (sidx >= biStart) {
            BI_CHUNK;
            gemm3_bi4<<<4 * encGy + cnt, 256, 0, stream>>>(
                XA, wtL + 65536, cb1 + (size_t)i * DI, nullptr,
                nullptr, nullptr, Hb, Menc, DI, D, 1, encGy,
                ego, side, W1t, W2t, b1, b2, outAgg, Nn, base, cnt);
        } else {
            SPMM_CHUNK;
            gemm3_spmm<<<4 * encGy + cnt, 256, 0, stream>>>(
                XA, wtL + 65536, cb1 + (size_t)i * DI, nullptr,
                nullptr, nullptr, Hb, Menc, DI, D, 1, encGy,
                egob, vals, rows, cols, side, nnz, base, 4 * encGy);
        }

        // --- FFN down + residual + LN2 ---
        sidx++;
        float* dst = (i == NL - 1) ? outX : XB;
        if (sidx >= biStart) {
            BI_CHUNK;
            gemm3_bi4<<<encGy + cnt, 256, 0, stream>>>(
                Hb, wtL + 131072, cb2 + (size_t)i * D, XA,
                ln2_g + (size_t)i * D, ln2_b + (size_t)i * D, dst, Menc, D, DI, 0, encGy,
                ego, side, W1t, W2t, b1, b2, outAgg, Nn, base, cnt);
        } else {
            SPMM_CHUNK;
            gemm3_spmm<<<encGy + cnt, 256, 0, stream>>>(
                Hb, wtL + 131072, cb2 + (size_t)i * D, XA,
                ln2_g + (size_t)i * D, ln2_b + (size_t)i * D, dst, Menc, D, DI, 0, encGy,
                egob, vals, rows, cols, side, nnz, base, encGy);
        }
        #undef SPMM_CHUNK
        #undef BI_CHUNK
        x = XB;
    }
}